// Round 5
// baseline (251.380 us; speedup 1.0000x reference)
//
#include <hip/hip_runtime.h>
#include <stdint.h>

#define ALPHA 1.702f
#define LIMIT 7.0f

typedef float f32x4 __attribute__((ext_vector_type(4)));
typedef __bf16 bf16x8 __attribute__((ext_vector_type(8)));

static __device__ __forceinline__ unsigned short f2bf(float f) {
    union { float f; uint32_t u; } v; v.f = f;
    uint32_t u = v.u;
    return (unsigned short)((u + 0x7FFFu + ((u >> 16) & 1u)) >> 16);
}

#define GLL16(GP, LP) __builtin_amdgcn_global_load_lds( \
    (const __attribute__((address_space(1))) void*)(GP), \
    (__attribute__((address_space(3))) void*)(LP), 16, 0, 0)

// Conflict-free LDS swizzle (R3-verified: SQ_LDS_BANK_CONFLICT = 0).
static __device__ __forceinline__ int lsw(int row, int kc) {
    return row * 4 + (kc ^ ((row >> 1) & 3));
}

// ---------------------------------------------------------------------------
// prep: blocks [0,6144): fp32->bf16 convert (W1 permuted glu/lin halves);
//       block 0 also zeros done[128]. blocks [6144,6400): gate + RMSNorm +
//       coeff + out init + NON-ATOMIC aux partials to paux[bid][48].
// ---------------------------------------------------------------------------
__global__ __launch_bounds__(256) void prep_kernel(
    const float* __restrict__ w1, const float* __restrict__ w2,
    unsigned short* __restrict__ w1p, unsigned short* __restrict__ w2b,
    const float* __restrict__ x,
    const float* __restrict__ norm_scale,
    const float* __restrict__ gate_w,
    const float* __restrict__ gate_b,
    const float* __restrict__ b2,
    unsigned short* __restrict__ t_bf,
    float* __restrict__ coeff,
    float* __restrict__ paux,     // [256][48]
    int* __restrict__ done,       // [16][8] zeroed here
    float* __restrict__ out)
{
    __shared__ float red[4][48];
    if (blockIdx.x < 6144) {
        if (blockIdx.x == 0 && threadIdx.x < 128) done[threadIdx.x & 127] = 0;
        const int idx = blockIdx.x * 256 + threadIdx.x;
        const int n1 = 1048576;
        if (idx < n1) {
            const int e = idx >> 17;
            const int rem = idx & 131071;
            const int r = rem >> 7;
            const int c = rem & 127;
            const int src = (r < 512) ? (2 * r) : (2 * (r - 512) + 1);
            float4 v = ((const float4*)w1)[(e << 17) + (src << 7) + c];
            ushort4 o = { f2bf(v.x), f2bf(v.y), f2bf(v.z), f2bf(v.w) };
            ((ushort4*)w1p)[idx] = o;
        } else {
            const int i2 = idx - n1;
            float4 v = ((const float4*)w2)[i2];
            ushort4 o = { f2bf(v.x), f2bf(v.y), f2bf(v.z), f2bf(v.w) };
            ((ushort4*)w2b)[i2] = o;
        }
        return;
    }
    const int bid = blockIdx.x - 6144;
    const int wave = threadIdx.x >> 6;
    const int lane = threadIdx.x & 63;

    float accP[8], accI[8], accC[32];
    #pragma unroll
    for (int e = 0; e < 8; ++e) { accP[e] = 0.f; accI[e] = 0.f; }
    #pragma unroll
    for (int i = 0; i < 32; ++i) accC[i] = 0.f;

    #pragma unroll
    for (int it = 0; it < 2; ++it) {
        const int t = bid * 8 + wave * 2 + it;
        const float4* xr = (const float4*)(x + t * 512);
        float4 x0 = xr[lane * 2];
        float4 x1 = xr[lane * 2 + 1];
        float ss = x0.x*x0.x + x0.y*x0.y + x0.z*x0.z + x0.w*x0.w
                 + x1.x*x1.x + x1.y*x1.y + x1.z*x1.z + x1.w*x1.w;
        #pragma unroll
        for (int off = 32; off > 0; off >>= 1) ss += __shfl_xor(ss, off, 64);
        const float rstd = rsqrtf(ss * (1.f / 512.f) + 1e-6f);
        const float4* sr = (const float4*)norm_scale;
        float4 s0 = sr[lane * 2], s1 = sr[lane * 2 + 1];
        float tv[8];
        tv[0] = x0.x * rstd * s0.x; tv[1] = x0.y * rstd * s0.y;
        tv[2] = x0.z * rstd * s0.z; tv[3] = x0.w * rstd * s0.w;
        tv[4] = x1.x * rstd * s1.x; tv[5] = x1.y * rstd * s1.y;
        tv[6] = x1.z * rstd * s1.z; tv[7] = x1.w * rstd * s1.w;
        uint32_t p0 = (uint32_t)f2bf(tv[0]) | ((uint32_t)f2bf(tv[1]) << 16);
        uint32_t p1 = (uint32_t)f2bf(tv[2]) | ((uint32_t)f2bf(tv[3]) << 16);
        uint32_t p2 = (uint32_t)f2bf(tv[4]) | ((uint32_t)f2bf(tv[5]) << 16);
        uint32_t p3 = (uint32_t)f2bf(tv[6]) | ((uint32_t)f2bf(tv[7]) << 16);
        uint4 pk; pk.x = p0; pk.y = p1; pk.z = p2; pk.w = p3;
        ((uint4*)(t_bf + t * 512))[lane] = pk;
        float le[8];
        #pragma unroll
        for (int e = 0; e < 8; ++e) {
            const float4* gw = (const float4*)(gate_w + e * 512);
            float4 g0 = gw[lane * 2], g1 = gw[lane * 2 + 1];
            float d = tv[0]*g0.x + tv[1]*g0.y + tv[2]*g0.z + tv[3]*g0.w
                    + tv[4]*g1.x + tv[5]*g1.y + tv[6]*g1.z + tv[7]*g1.w;
            #pragma unroll
            for (int off = 32; off > 0; off >>= 1) d += __shfl_xor(d, off, 64);
            le[e] = d + gate_b[e];
        }
        float mx = le[0];
        #pragma unroll
        for (int e = 1; e < 8; ++e) mx = fmaxf(mx, le[e]);
        float pe[8], se = 0.f;
        #pragma unroll
        for (int e = 0; e < 8; ++e) { pe[e] = __expf(le[e] - mx); se += pe[e]; }
        const float sinv = 1.f / se;
        #pragma unroll
        for (int e = 0; e < 8; ++e) pe[e] *= sinv;
        unsigned picked = 0;
        int ik[4]; float wk[4];
        #pragma unroll
        for (int k = 0; k < 4; ++k) {
            float bv = -1.f; int bi = 0;
            #pragma unroll
            for (int e = 0; e < 8; ++e)
                if (!(picked & (1u << e)) && pe[e] > bv) { bv = pe[e]; bi = e; }
            ik[k] = bi; wk[k] = bv; picked |= (1u << bi);
        }
        const float winv = 1.f / (wk[0] + wk[1] + wk[2] + wk[3]);
        float nw[4];
        #pragma unroll
        for (int k = 0; k < 4; ++k) nw[k] = wk[k] * winv;
        float ce[8];
        #pragma unroll
        for (int e = 0; e < 8; ++e) {
            float c = 0.f;
            #pragma unroll
            for (int k = 0; k < 4; ++k) c += (ik[k] == e) ? nw[k] : 0.f;
            ce[e] = c;
        }
        if (lane == 0) {
            #pragma unroll
            for (int e = 0; e < 8; ++e) coeff[t * 8 + e] = ce[e];
        }
        #pragma unroll
        for (int e = 0; e < 8; ++e) { accP[e] += pe[e]; accI[e] += le[e]; }
        #pragma unroll
        for (int k = 0; k < 4; ++k)
            #pragma unroll
            for (int e = 0; e < 8; ++e)
                accC[k * 8 + e] += (ik[k] == e) ? 1.f : 0.f;
        float ov[8];
        ov[0] = x0.x; ov[1] = x0.y; ov[2] = x0.z; ov[3] = x0.w;
        ov[4] = x1.x; ov[5] = x1.y; ov[6] = x1.z; ov[7] = x1.w;
        #pragma unroll
        for (int e = 0; e < 8; ++e) {
            const float4* br = (const float4*)(b2 + e * 512);
            float4 b0 = br[lane * 2], bb1 = br[lane * 2 + 1];
            ov[0] += ce[e] * b0.x; ov[1] += ce[e] * b0.y;
            ov[2] += ce[e] * b0.z; ov[3] += ce[e] * b0.w;
            ov[4] += ce[e] * bb1.x; ov[5] += ce[e] * bb1.y;
            ov[6] += ce[e] * bb1.z; ov[7] += ce[e] * bb1.w;
        }
        float4 o0, o1;
        o0.x = ov[0]; o0.y = ov[1]; o0.z = ov[2]; o0.w = ov[3];
        o1.x = ov[4]; o1.y = ov[5]; o1.z = ov[6]; o1.w = ov[7];
        float4* orow = (float4*)(out + t * 512);
        orow[lane * 2] = o0; orow[lane * 2 + 1] = o1;
    }
    if (lane == 0) {
        #pragma unroll
        for (int e = 0; e < 8; ++e) { red[wave][e] = accP[e]; red[wave][8 + e] = accI[e]; }
        #pragma unroll
        for (int i = 0; i < 32; ++i) red[wave][16 + i] = accC[i];
    }
    __syncthreads();
    if (threadIdx.x < 48) {
        paux[bid * 48 + threadIdx.x] =
            red[0][threadIdx.x] + red[1][threadIdx.x]
          + red[2][threadIdx.x] + red[3][threadIdx.x];
    }
}

// ---------------------------------------------------------------------------
// fused_gemm: 512 persistent blocks, all co-resident (54 KB LDS -> max 2/CU).
// Phase A: gemm1+swiglu tile (bx -> 16m x 32p), signal done[m][e] (4 per m,e).
// Block 0 additionally reduces aux partials. Phase B: gemm2 split-K-by-expert
// tile (bx -> 4n x 16m x 8e), spin-wait done[m][e]==4, atomicAdd into out.
// ---------------------------------------------------------------------------
__global__ __launch_bounds__(256, 2) void fused_gemm(
    const unsigned short* __restrict__ A,    // t_bf [2048][512]
    const unsigned short* __restrict__ w1p,  // [8][1024][512] glu/lin split
    const float* __restrict__ b1,            // [8][1024] interleaved
    const float* __restrict__ coeff,         // [2048][8]
    unsigned short* __restrict__ As,         // [2048][4096]
    const unsigned short* __restrict__ w2b,  // [8][512][512]
    float* __restrict__ out,                 // [2048][512] pre-initialized
    const float* __restrict__ paux,          // [256][48]
    float* __restrict__ aux_out,
    int* __restrict__ done)                  // [16][8]
{
    __shared__ unsigned short smem[6][4608];   // 54 KB -> <=2 blocks/CU
    const int tid = threadIdx.x;
    const int bx = blockIdx.x;
    const int lane = tid & 63, wave = tid >> 6;
    const int wm = (wave & 1) * 64, wn = (wave >> 1) * 64;
    const int quad = lane >> 4, l16 = lane & 15;
    const int srow = tid >> 2;
    const int soff = ((tid & 3) ^ ((tid >> 3) & 3)) * 8;

    int rA[4], rB[4];
    #pragma unroll
    for (int i = 0; i < 4; ++i) {
        rA[i] = lsw(wm + i * 16 + l16, quad) * 8;
        rB[i] = lsw(wn + i * 16 + l16, quad) * 8;
    }

    // ================= Phase A: GEMM1 + swiglu =================
    {
        const int tile_p = bx & 31, tile_m = bx >> 5;
        const int e = tile_p >> 2;
        const int np = (tile_p & 3) * 128;
        const int m0 = tile_m * 128;

        const unsigned short* Ar0 = A + (m0 + srow) * 512 + soff;
        const unsigned short* Ar1 = A + (m0 + 64 + srow) * 512 + soff;
        const unsigned short* Bg = w1p + (e * 1024 + np) * 512;
        const unsigned short* Bg0 = Bg + srow * 512 + soff;
        const unsigned short* Bg1 = Bg + (64 + srow) * 512 + soff;
        const unsigned short* Bl0 = Bg0 + 512 * 512;
        const unsigned short* Bl1 = Bg1 + 512 * 512;

        f32x4 accG[4][4], accL[4][4];
        #pragma unroll
        for (int i = 0; i < 4; ++i)
            #pragma unroll
            for (int j = 0; j < 4; ++j) {
                f32x4 z = {0.f, 0.f, 0.f, 0.f};
                accG[i][j] = z; accL[i][j] = z;
            }

#define STAGE1(s, k0) do { \
    GLL16(Ar0 + (k0), smem[(s)*3+0] + tid * 8); \
    GLL16(Ar1 + (k0), smem[(s)*3+0] + (tid + 256) * 8); \
    GLL16(Bg0 + (k0), smem[(s)*3+1] + tid * 8); \
    GLL16(Bg1 + (k0), smem[(s)*3+1] + (tid + 256) * 8); \
    GLL16(Bl0 + (k0), smem[(s)*3+2] + tid * 8); \
    GLL16(Bl1 + (k0), smem[(s)*3+2] + (tid + 256) * 8); \
} while (0)

        STAGE1(0, 0);
        STAGE1(1, 32);
        #pragma unroll
        for (int kt = 0; kt < 16; ++kt) {
            const int cur = kt & 1;
            if (kt < 15) asm volatile("s_waitcnt vmcnt(6)" ::: "memory");
            else         asm volatile("s_waitcnt vmcnt(0)" ::: "memory");
            asm volatile("s_barrier" ::: "memory");
            bf16x8 af[4], bg[4], bl[4];
            #pragma unroll
            for (int i = 0; i < 4; ++i) {
                af[i] = *(const bf16x8*)(smem[cur*3+0] + rA[i]);
                bg[i] = *(const bf16x8*)(smem[cur*3+1] + rB[i]);
                bl[i] = *(const bf16x8*)(smem[cur*3+2] + rB[i]);
            }
            asm volatile("s_waitcnt lgkmcnt(0)" ::: "memory");
            asm volatile("s_barrier" ::: "memory");
            if (kt < 14) STAGE1(cur, (kt + 2) * 32);
            #pragma unroll
            for (int i = 0; i < 4; ++i)
                #pragma unroll
                for (int j = 0; j < 4; ++j) {
                    accG[i][j] = __builtin_amdgcn_mfma_f32_16x16x32_bf16(af[i], bg[j], accG[i][j], 0, 0, 0);
                    accL[i][j] = __builtin_amdgcn_mfma_f32_16x16x32_bf16(af[i], bl[j], accL[i][j], 0, 0, 0);
                }
        }
#undef STAGE1

        float cw[4][4];
        #pragma unroll
        for (int i = 0; i < 4; ++i) {
            const int rowb = m0 + wm + i * 16 + quad * 4;
            #pragma unroll
            for (int r = 0; r < 4; ++r) cw[i][r] = coeff[(rowb + r) * 8 + e];
        }
        #pragma unroll
        for (int j = 0; j < 4; ++j) {
            const int colp = np + wn + j * 16 + l16;
            const float bgv = b1[e * 1024 + 2 * colp];
            const float blv = b1[e * 1024 + 2 * colp + 1];
            #pragma unroll
            for (int i = 0; i < 4; ++i) {
                const int rowb = m0 + wm + i * 16 + quad * 4;
                #pragma unroll
                for (int r = 0; r < 4; ++r) {
                    float g = fminf(fmaxf(accG[i][j][r] + bgv, -LIMIT), LIMIT);
                    float l = fminf(fmaxf(accL[i][j][r] + blv, -LIMIT), LIMIT);
                    float a = g / (1.f + __expf(-ALPHA * g)) + l + 1.f;
                    a *= cw[i][r];
                    As[(rowb + r) * 4096 + e * 512 + colp] = f2bf(a);
                }
            }
        }
        __threadfence();
        __syncthreads();
        if (tid == 0)
            __hip_atomic_fetch_add(&done[tile_m * 8 + e], 1,
                                   __ATOMIC_RELEASE, __HIP_MEMORY_SCOPE_AGENT);
    }

    // ================= aux loss (block 0 only) =================
    if (bx == 0) {
        float* sred = (float*)(smem[5] + 4096);   // unused tail region
        if (tid < 48) {
            float s = 0.f;
            for (int b = 0; b < 256; ++b) s += paux[b * 48 + tid];
            sred[tid] = s;
        }
        __syncthreads();
        if (tid == 0) {
            float imp[8], sl = 0.f;
            #pragma unroll
            for (int e = 0; e < 8; ++e) {
                float P = sred[e] * (1.f / 2048.f);
                imp[e] = sred[8 + e];
                float D = (16.f * sred[16 + e] + 8.f * sred[24 + e]
                         + 4.f * sred[32 + e] + 2.f * sred[40 + e]) * (1.f / 8192.f);
                sl += P * D;
            }
            float loss_load = 0.01f * 8.f * sl;
            float mean = 0.f;
            #pragma unroll
            for (int e = 0; e < 8; ++e) mean += imp[e];
            mean *= 0.125f;
            float var = 0.f;
            #pragma unroll
            for (int e = 0; e < 8; ++e) { float d = imp[e] - mean; var += d * d; }
            var *= (1.f / 7.f);
            float cv = sqrtf(var) / (mean + 1e-6f);
            *aux_out = loss_load + 0.01f * cv * cv;
        }
    }

    // ================= Phase B: GEMM2 (split-K by expert) =================
    {
        const int tile_n = bx & 3;
        const int tile_m = (bx >> 2) & 15;
        const int e = bx >> 6;
        const int m0 = tile_m * 128, n0 = tile_n * 128;

        if (tid == 0) {
            while (__hip_atomic_load(&done[tile_m * 8 + e],
                                     __ATOMIC_ACQUIRE, __HIP_MEMORY_SCOPE_AGENT) < 4)
                __builtin_amdgcn_s_sleep(2);
        }
        __syncthreads();

        const unsigned short* Ar0 = As + (m0 + srow) * 4096 + e * 512 + soff;
        const unsigned short* Ar1 = As + (m0 + 64 + srow) * 4096 + e * 512 + soff;
        const unsigned short* Bb  = w2b + e * 262144;
        const unsigned short* Br0 = Bb + (n0 + srow) * 512 + soff;
        const unsigned short* Br1 = Bb + (n0 + 64 + srow) * 512 + soff;

        f32x4 acc[4][4];
        #pragma unroll
        for (int i = 0; i < 4; ++i)
            #pragma unroll
            for (int j = 0; j < 4; ++j) { f32x4 z = {0.f, 0.f, 0.f, 0.f}; acc[i][j] = z; }

#define STAGE2(s, k0) do { \
    GLL16(Ar0 + (k0), smem[(s)*3+0] + tid * 8); \
    GLL16(Ar1 + (k0), smem[(s)*3+0] + (tid + 256) * 8); \
    GLL16(Br0 + (k0), smem[(s)*3+1] + tid * 8); \
    GLL16(Br1 + (k0), smem[(s)*3+1] + (tid + 256) * 8); \
} while (0)

        STAGE2(0, 0);
        STAGE2(1, 32);
        #pragma unroll
        for (int kt = 0; kt < 16; ++kt) {
            const int cur = kt & 1;
            if (kt < 15) asm volatile("s_waitcnt vmcnt(4)" ::: "memory");
            else         asm volatile("s_waitcnt vmcnt(0)" ::: "memory");
            asm volatile("s_barrier" ::: "memory");
            bf16x8 af[4], bf[4];
            #pragma unroll
            for (int i = 0; i < 4; ++i) {
                af[i] = *(const bf16x8*)(smem[cur*3+0] + rA[i]);
                bf[i] = *(const bf16x8*)(smem[cur*3+1] + rB[i]);
            }
            asm volatile("s_waitcnt lgkmcnt(0)" ::: "memory");
            asm volatile("s_barrier" ::: "memory");
            if (kt < 14) STAGE2(cur, (kt + 2) * 32);
            #pragma unroll
            for (int i = 0; i < 4; ++i)
                #pragma unroll
                for (int j = 0; j < 4; ++j)
                    acc[i][j] = __builtin_amdgcn_mfma_f32_16x16x32_bf16(af[i], bf[j], acc[i][j], 0, 0, 0);
        }
#undef STAGE2

        #pragma unroll
        for (int j = 0; j < 4; ++j) {
            const int col = n0 + wn + j * 16 + l16;
            #pragma unroll
            for (int i = 0; i < 4; ++i) {
                const int rowb = m0 + wm + i * 16 + quad * 4;
                #pragma unroll
                for (int r = 0; r < 4; ++r)
                    atomicAdd(&out[(rowb + r) * 512 + col], acc[i][j][r]);
            }
        }
    }
}

// ---------------------------------------------------------------------------
extern "C" void kernel_launch(void* const* d_in, const int* in_sizes, int n_in,
                              void* d_out, int out_size, void* d_ws, size_t ws_size,
                              hipStream_t stream)
{
    (void)in_sizes; (void)n_in; (void)out_size; (void)ws_size;
    const float* x          = (const float*)d_in[0];
    const float* norm_scale = (const float*)d_in[1];
    const float* gate_w     = (const float*)d_in[2];
    const float* gate_b     = (const float*)d_in[3];
    const float* mlp1_w     = (const float*)d_in[4];
    const float* mlp1_b     = (const float*)d_in[5];
    const float* mlp2_w     = (const float*)d_in[6];
    const float* mlp2_b     = (const float*)d_in[7];
    float* out = (float*)d_out;

    char* ws = (char*)d_ws;
    unsigned short* w1p   = (unsigned short*)(ws);              // 8,388,608 B
    unsigned short* w2b   = (unsigned short*)(ws + 8388608);    // 4,194,304 B
    unsigned short* tbf   = (unsigned short*)(ws + 12582912);   // 2,097,152 B
    unsigned short* As    = (unsigned short*)(ws + 14680064);   // 16,777,216 B
    float*          coeff = (float*)(ws + 31457280);            // 65,536 B
    float*          paux  = (float*)(ws + 31522816);            // 49,152 B
    int*            done  = (int*)(ws + 31571968);              // 512 B

    prep_kernel<<<6400, 256, 0, stream>>>(mlp1_w, mlp2_w, w1p, w2b,
                                          x, norm_scale, gate_w, gate_b, mlp2_b,
                                          tbf, coeff, paux, done, out);
    fused_gemm<<<512, 256, 0, stream>>>(tbf, w1p, mlp1_b, coeff, As, w2b, out,
                                        paux, out + 2048 * 512, done);
}

// Round 6
// 179.767 us; speedup vs baseline: 1.3984x; 1.3984x over previous
//
#include <hip/hip_runtime.h>
#include <stdint.h>

#define ALPHA 1.702f
#define LIMIT 7.0f

typedef float f32x4 __attribute__((ext_vector_type(4)));
typedef __bf16 bf16x8 __attribute__((ext_vector_type(8)));

static __device__ __forceinline__ unsigned short f2bf(float f) {
    union { float f; uint32_t u; } v; v.f = f;
    uint32_t u = v.u;
    return (unsigned short)((u + 0x7FFFu + ((u >> 16) & 1u)) >> 16);
}

#define GLL16(GP, LP) __builtin_amdgcn_global_load_lds( \
    (const __attribute__((address_space(1))) void*)(GP), \
    (__attribute__((address_space(3))) void*)(LP), 16, 0, 0)

// Conflict-free LDS swizzle (R3-verified: SQ_LDS_BANK_CONFLICT = 0).
// Staging unit u holds (row=u>>2, kc=(u&3)^((u>>3)&3)); lsw() is the inverse.
static __device__ __forceinline__ int lsw(int row, int kc) {
    return row * 4 + (kc ^ ((row >> 1) & 3));
}

// ---------------------------------------------------------------------------
// prep: blocks [0,6144): fp32->bf16 convert (W1 permuted glu/lin halves).
//       blocks [6144,6400): gate + RMSNorm + coeff + out init + non-atomic
//       aux partials to paux[bid][48].
// ---------------------------------------------------------------------------
__global__ __launch_bounds__(256) void prep_kernel(
    const float* __restrict__ w1, const float* __restrict__ w2,
    unsigned short* __restrict__ w1p, unsigned short* __restrict__ w2b,
    const float* __restrict__ x,
    const float* __restrict__ norm_scale,
    const float* __restrict__ gate_w,
    const float* __restrict__ gate_b,
    const float* __restrict__ b2,
    unsigned short* __restrict__ t_bf,
    float* __restrict__ coeff,
    float* __restrict__ paux,     // [256][48]
    float* __restrict__ out)
{
    __shared__ float red[4][48];
    if (blockIdx.x < 6144) {
        const int idx = blockIdx.x * 256 + threadIdx.x;
        const int n1 = 1048576;
        if (idx < n1) {
            const int e = idx >> 17;
            const int rem = idx & 131071;
            const int r = rem >> 7;
            const int c = rem & 127;
            const int src = (r < 512) ? (2 * r) : (2 * (r - 512) + 1);
            float4 v = ((const float4*)w1)[(e << 17) + (src << 7) + c];
            ushort4 o = { f2bf(v.x), f2bf(v.y), f2bf(v.z), f2bf(v.w) };
            ((ushort4*)w1p)[idx] = o;
        } else {
            const int i2 = idx - n1;
            float4 v = ((const float4*)w2)[i2];
            ushort4 o = { f2bf(v.x), f2bf(v.y), f2bf(v.z), f2bf(v.w) };
            ((ushort4*)w2b)[i2] = o;
        }
        return;
    }
    const int bid = blockIdx.x - 6144;
    const int wave = threadIdx.x >> 6;
    const int lane = threadIdx.x & 63;

    float accP[8], accI[8], accC[32];
    #pragma unroll
    for (int e = 0; e < 8; ++e) { accP[e] = 0.f; accI[e] = 0.f; }
    #pragma unroll
    for (int i = 0; i < 32; ++i) accC[i] = 0.f;

    #pragma unroll
    for (int it = 0; it < 2; ++it) {
        const int t = bid * 8 + wave * 2 + it;
        const float4* xr = (const float4*)(x + t * 512);
        float4 x0 = xr[lane * 2];
        float4 x1 = xr[lane * 2 + 1];
        float ss = x0.x*x0.x + x0.y*x0.y + x0.z*x0.z + x0.w*x0.w
                 + x1.x*x1.x + x1.y*x1.y + x1.z*x1.z + x1.w*x1.w;
        #pragma unroll
        for (int off = 32; off > 0; off >>= 1) ss += __shfl_xor(ss, off, 64);
        const float rstd = rsqrtf(ss * (1.f / 512.f) + 1e-6f);
        const float4* sr = (const float4*)norm_scale;
        float4 s0 = sr[lane * 2], s1 = sr[lane * 2 + 1];
        float tv[8];
        tv[0] = x0.x * rstd * s0.x; tv[1] = x0.y * rstd * s0.y;
        tv[2] = x0.z * rstd * s0.z; tv[3] = x0.w * rstd * s0.w;
        tv[4] = x1.x * rstd * s1.x; tv[5] = x1.y * rstd * s1.y;
        tv[6] = x1.z * rstd * s1.z; tv[7] = x1.w * rstd * s1.w;
        uint32_t p0 = (uint32_t)f2bf(tv[0]) | ((uint32_t)f2bf(tv[1]) << 16);
        uint32_t p1 = (uint32_t)f2bf(tv[2]) | ((uint32_t)f2bf(tv[3]) << 16);
        uint32_t p2 = (uint32_t)f2bf(tv[4]) | ((uint32_t)f2bf(tv[5]) << 16);
        uint32_t p3 = (uint32_t)f2bf(tv[6]) | ((uint32_t)f2bf(tv[7]) << 16);
        uint4 pk; pk.x = p0; pk.y = p1; pk.z = p2; pk.w = p3;
        ((uint4*)(t_bf + t * 512))[lane] = pk;
        float le[8];
        #pragma unroll
        for (int e = 0; e < 8; ++e) {
            const float4* gw = (const float4*)(gate_w + e * 512);
            float4 g0 = gw[lane * 2], g1 = gw[lane * 2 + 1];
            float d = tv[0]*g0.x + tv[1]*g0.y + tv[2]*g0.z + tv[3]*g0.w
                    + tv[4]*g1.x + tv[5]*g1.y + tv[6]*g1.z + tv[7]*g1.w;
            #pragma unroll
            for (int off = 32; off > 0; off >>= 1) d += __shfl_xor(d, off, 64);
            le[e] = d + gate_b[e];
        }
        float mx = le[0];
        #pragma unroll
        for (int e = 1; e < 8; ++e) mx = fmaxf(mx, le[e]);
        float pe[8], se = 0.f;
        #pragma unroll
        for (int e = 0; e < 8; ++e) { pe[e] = __expf(le[e] - mx); se += pe[e]; }
        const float sinv = 1.f / se;
        #pragma unroll
        for (int e = 0; e < 8; ++e) pe[e] *= sinv;
        unsigned picked = 0;
        int ik[4]; float wk[4];
        #pragma unroll
        for (int k = 0; k < 4; ++k) {
            float bv = -1.f; int bi = 0;
            #pragma unroll
            for (int e = 0; e < 8; ++e)
                if (!(picked & (1u << e)) && pe[e] > bv) { bv = pe[e]; bi = e; }
            ik[k] = bi; wk[k] = bv; picked |= (1u << bi);
        }
        const float winv = 1.f / (wk[0] + wk[1] + wk[2] + wk[3]);
        float nw[4];
        #pragma unroll
        for (int k = 0; k < 4; ++k) nw[k] = wk[k] * winv;
        float ce[8];
        #pragma unroll
        for (int e = 0; e < 8; ++e) {
            float c = 0.f;
            #pragma unroll
            for (int k = 0; k < 4; ++k) c += (ik[k] == e) ? nw[k] : 0.f;
            ce[e] = c;
        }
        if (lane == 0) {
            #pragma unroll
            for (int e = 0; e < 8; ++e) coeff[t * 8 + e] = ce[e];
        }
        #pragma unroll
        for (int e = 0; e < 8; ++e) { accP[e] += pe[e]; accI[e] += le[e]; }
        #pragma unroll
        for (int k = 0; k < 4; ++k)
            #pragma unroll
            for (int e = 0; e < 8; ++e)
                accC[k * 8 + e] += (ik[k] == e) ? 1.f : 0.f;
        float ov[8];
        ov[0] = x0.x; ov[1] = x0.y; ov[2] = x0.z; ov[3] = x0.w;
        ov[4] = x1.x; ov[5] = x1.y; ov[6] = x1.z; ov[7] = x1.w;
        #pragma unroll
        for (int e = 0; e < 8; ++e) {
            const float4* br = (const float4*)(b2 + e * 512);
            float4 b0 = br[lane * 2], bb1 = br[lane * 2 + 1];
            ov[0] += ce[e] * b0.x; ov[1] += ce[e] * b0.y;
            ov[2] += ce[e] * b0.z; ov[3] += ce[e] * b0.w;
            ov[4] += ce[e] * bb1.x; ov[5] += ce[e] * bb1.y;
            ov[6] += ce[e] * bb1.z; ov[7] += ce[e] * bb1.w;
        }
        float4 o0, o1;
        o0.x = ov[0]; o0.y = ov[1]; o0.z = ov[2]; o0.w = ov[3];
        o1.x = ov[4]; o1.y = ov[5]; o1.z = ov[6]; o1.w = ov[7];
        float4* orow = (float4*)(out + t * 512);
        orow[lane * 2] = o0; orow[lane * 2 + 1] = o1;
    }
    if (lane == 0) {
        #pragma unroll
        for (int e = 0; e < 8; ++e) { red[wave][e] = accP[e]; red[wave][8 + e] = accI[e]; }
        #pragma unroll
        for (int i = 0; i < 32; ++i) red[wave][16 + i] = accC[i];
    }
    __syncthreads();
    if (threadIdx.x < 48) {
        paux[bid * 48 + threadIdx.x] =
            red[0][threadIdx.x] + red[1][threadIdx.x]
          + red[2][threadIdx.x] + red[3][threadIdx.x];
    }
}

// ---------------------------------------------------------------------------
// GEMM1 + swiglu*coeff. Tile 256 rows x 128 activation cols (glu+lin pair),
// BK=32, double-buffered (64 KB LDS), prefetch dist 2, fine vmcnt.
// grid 256 = 8 m-tiles x 32 (e,np) groups. 1 block/CU.
// ---------------------------------------------------------------------------
__global__ __launch_bounds__(256, 1) void gemm1_swiglu(
    const unsigned short* __restrict__ A,    // t_bf [2048][512]
    const unsigned short* __restrict__ w1p,  // [8][1024][512] glu/lin split
    const float* __restrict__ b1,            // [8][1024] interleaved
    const float* __restrict__ coeff,         // [2048][8]
    unsigned short* __restrict__ As)         // [2048][4096]
{
    __shared__ unsigned short tA[2][8192];   // 256x32 per buf (16 KB x2)
    __shared__ unsigned short tBg[2][4096];  // 128x32 per buf (8 KB x2)
    __shared__ unsigned short tBl[2][4096];
    const int tid = threadIdx.x;
    const int bx = blockIdx.x;
    const int g = bx & 31;                   // (e, np) group
    const int e = g >> 2;
    const int np = (g & 3) * 128;
    const int m0 = (bx >> 5) * 256;
    const int lane = tid & 63, wave = tid >> 6;
    const int wm = wave * 64;                // wave owns 64 rows, all 128 cols
    const int quad = lane >> 4, l16 = lane & 15;
    const int srow = tid >> 2;
    const int soff = ((tid & 3) ^ ((tid >> 3) & 3)) * 8;

    const unsigned short* Ar0 = A + (m0 + srow) * 512 + soff;
    const unsigned short* Ar1 = A + (m0 + 64 + srow) * 512 + soff;
    const unsigned short* Ar2 = A + (m0 + 128 + srow) * 512 + soff;
    const unsigned short* Ar3 = A + (m0 + 192 + srow) * 512 + soff;
    const unsigned short* Bg = w1p + (e * 1024 + np) * 512;
    const unsigned short* Bg0 = Bg + srow * 512 + soff;
    const unsigned short* Bg1 = Bg + (64 + srow) * 512 + soff;
    const unsigned short* Bl0 = Bg0 + 512 * 512;
    const unsigned short* Bl1 = Bg1 + 512 * 512;

    int rA[4], rB[8];
    #pragma unroll
    for (int i = 0; i < 4; ++i) rA[i] = lsw(wm + i * 16 + l16, quad) * 8;
    #pragma unroll
    for (int j = 0; j < 8; ++j) rB[j] = lsw(j * 16 + l16, quad) * 8;

    f32x4 accG[4][8], accL[4][8];
    #pragma unroll
    for (int i = 0; i < 4; ++i)
        #pragma unroll
        for (int j = 0; j < 8; ++j) {
            f32x4 z = {0.f, 0.f, 0.f, 0.f};
            accG[i][j] = z; accL[i][j] = z;
        }

#define STAGE1(s, k0) do { \
    GLL16(Ar0 + (k0), tA[s] + tid * 8); \
    GLL16(Ar1 + (k0), tA[s] + (tid + 256) * 8); \
    GLL16(Ar2 + (k0), tA[s] + (tid + 512) * 8); \
    GLL16(Ar3 + (k0), tA[s] + (tid + 768) * 8); \
    GLL16(Bg0 + (k0), tBg[s] + tid * 8); \
    GLL16(Bg1 + (k0), tBg[s] + (tid + 256) * 8); \
    GLL16(Bl0 + (k0), tBl[s] + tid * 8); \
    GLL16(Bl1 + (k0), tBl[s] + (tid + 256) * 8); \
} while (0)

    STAGE1(0, 0);
    STAGE1(1, 32);
    #pragma unroll
    for (int kt = 0; kt < 16; ++kt) {
        const int cur = kt & 1;
        if (kt < 15) asm volatile("s_waitcnt vmcnt(8)" ::: "memory");
        else         asm volatile("s_waitcnt vmcnt(0)" ::: "memory");
        asm volatile("s_barrier" ::: "memory");
        bf16x8 af[4];
        #pragma unroll
        for (int i = 0; i < 4; ++i) af[i] = *(const bf16x8*)(tA[cur] + rA[i]);
        bf16x8 bgf[8], blf[8];
        #pragma unroll
        for (int j = 0; j < 8; ++j) {
            bgf[j] = *(const bf16x8*)(tBg[cur] + rB[j]);
            blf[j] = *(const bf16x8*)(tBl[cur] + rB[j]);
        }
        asm volatile("s_waitcnt lgkmcnt(0)" ::: "memory");
        asm volatile("s_barrier" ::: "memory");
        if (kt < 14) STAGE1(cur, (kt + 2) * 32);
        #pragma unroll
        for (int j = 0; j < 8; ++j)
            #pragma unroll
            for (int i = 0; i < 4; ++i) {
                accG[i][j] = __builtin_amdgcn_mfma_f32_16x16x32_bf16(af[i], bgf[j], accG[i][j], 0, 0, 0);
                accL[i][j] = __builtin_amdgcn_mfma_f32_16x16x32_bf16(af[i], blf[j], accL[i][j], 0, 0, 0);
            }
    }
#undef STAGE1

    float cw[4][4];
    #pragma unroll
    for (int i = 0; i < 4; ++i) {
        const int rowb = m0 + wm + i * 16 + quad * 4;
        #pragma unroll
        for (int r = 0; r < 4; ++r) cw[i][r] = coeff[(rowb + r) * 8 + e];
    }
    #pragma unroll
    for (int j = 0; j < 8; ++j) {
        const int colp = np + j * 16 + l16;
        const float bgv = b1[e * 1024 + 2 * colp];
        const float blv = b1[e * 1024 + 2 * colp + 1];
        #pragma unroll
        for (int i = 0; i < 4; ++i) {
            const int rowb = m0 + wm + i * 16 + quad * 4;
            #pragma unroll
            for (int r = 0; r < 4; ++r) {
                float gv = fminf(fmaxf(accG[i][j][r] + bgv, -LIMIT), LIMIT);
                float lv = fminf(fmaxf(accL[i][j][r] + blv, -LIMIT), LIMIT);
                float a = gv / (1.f + __expf(-ALPHA * gv)) + lv + 1.f;
                a *= cw[i][r];
                As[(rowb + r) * 4096 + e * 512 + colp] = f2bf(a);
            }
        }
    }
}

// ---------------------------------------------------------------------------
// GEMM2 split-K=8 (expert slices), 128x128 tiles, 4-deep LDS pipeline
// (64 KB, prefetch dist 3), fp32 atomicAdd into pre-initialized out.
// grid 513 = 4n x 16m x 8e (+ block 512 = aux loss from paux).
// ---------------------------------------------------------------------------
__global__ __launch_bounds__(256, 2) void gemm2(
    const unsigned short* __restrict__ As,  // [2048][4096]
    const unsigned short* __restrict__ w2b, // [8][512][512]
    float* __restrict__ out,                // [2048][512]
    const float* __restrict__ paux,         // [256][48]
    float* __restrict__ aux_out)
{
    __shared__ unsigned short tA[4][4096];  // 128x32 per buf
    __shared__ unsigned short tB[4][4096];
    const int tid = threadIdx.x;
    const int bx = blockIdx.x;

    if (bx == 512) {
        // aux reduction: 4 waves x 64 blocks each, counters in lanes 0..47
        __shared__ float sred[4][48];
        const int wv = tid >> 6, ln = tid & 63;
        if (ln < 48) {
            float s = 0.f;
            for (int b = 0; b < 64; ++b) s += paux[(wv * 64 + b) * 48 + ln];
            sred[wv][ln] = s;
        }
        __syncthreads();
        if (tid == 0) {
            float imp[8], sl = 0.f;
            #pragma unroll
            for (int e = 0; e < 8; ++e) {
                float a0 = sred[0][e] + sred[1][e] + sred[2][e] + sred[3][e];
                float P = a0 * (1.f / 2048.f);
                imp[e] = sred[0][8+e] + sred[1][8+e] + sred[2][8+e] + sred[3][8+e];
                float c0 = sred[0][16+e] + sred[1][16+e] + sred[2][16+e] + sred[3][16+e];
                float c1 = sred[0][24+e] + sred[1][24+e] + sred[2][24+e] + sred[3][24+e];
                float c2 = sred[0][32+e] + sred[1][32+e] + sred[2][32+e] + sred[3][32+e];
                float c3 = sred[0][40+e] + sred[1][40+e] + sred[2][40+e] + sred[3][40+e];
                float D = (16.f * c0 + 8.f * c1 + 4.f * c2 + 2.f * c3) * (1.f / 8192.f);
                sl += P * D;
            }
            float loss_load = 0.01f * 8.f * sl;
            float mean = 0.f;
            #pragma unroll
            for (int e = 0; e < 8; ++e) mean += imp[e];
            mean *= 0.125f;
            float var = 0.f;
            #pragma unroll
            for (int e = 0; e < 8; ++e) { float d = imp[e] - mean; var += d * d; }
            var *= (1.f / 7.f);
            float cv = sqrtf(var) / (mean + 1e-6f);
            *aux_out = loss_load + 0.01f * cv * cv;
        }
        return;
    }

    const int tile_n = bx & 3;
    const int tile_m = (bx >> 2) & 15;
    const int e = bx >> 6;
    const int m0 = tile_m * 128, n0 = tile_n * 128;
    const int lane = tid & 63, wave = tid >> 6;
    const int wm = (wave & 1) * 64, wn = (wave >> 1) * 64;
    const int quad = lane >> 4, l16 = lane & 15;
    const int srow = tid >> 2;
    const int soff = ((tid & 3) ^ ((tid >> 3) & 3)) * 8;

    const unsigned short* Ar0 = As + (m0 + srow) * 4096 + e * 512 + soff;
    const unsigned short* Ar1 = As + (m0 + 64 + srow) * 4096 + e * 512 + soff;
    const unsigned short* Bb  = w2b + e * 262144;
    const unsigned short* Br0 = Bb + (n0 + srow) * 512 + soff;
    const unsigned short* Br1 = Bb + (n0 + 64 + srow) * 512 + soff;

    int rA[4], rB[4];
    #pragma unroll
    for (int i = 0; i < 4; ++i) {
        rA[i] = lsw(wm + i * 16 + l16, quad) * 8;
        rB[i] = lsw(wn + i * 16 + l16, quad) * 8;
    }

    f32x4 acc[4][4];
    #pragma unroll
    for (int i = 0; i < 4; ++i)
        #pragma unroll
        for (int j = 0; j < 4; ++j) { f32x4 z = {0.f, 0.f, 0.f, 0.f}; acc[i][j] = z; }

#define STAGE2(s, k0) do { \
    GLL16(Ar0 + (k0), tA[s] + tid * 8); \
    GLL16(Ar1 + (k0), tA[s] + (tid + 256) * 8); \
    GLL16(Br0 + (k0), tB[s] + tid * 8); \
    GLL16(Br1 + (k0), tB[s] + (tid + 256) * 8); \
} while (0)

    STAGE2(0, 0);
    STAGE2(1, 32);
    STAGE2(2, 64);
    #pragma unroll
    for (int kt = 0; kt < 16; ++kt) {
        const int cur = kt & 3;
        if (kt <= 13)      asm volatile("s_waitcnt vmcnt(8)" ::: "memory");
        else if (kt == 14) asm volatile("s_waitcnt vmcnt(4)" ::: "memory");
        else               asm volatile("s_waitcnt vmcnt(0)" ::: "memory");
        asm volatile("s_barrier" ::: "memory");
        bf16x8 af[4], bf[4];
        #pragma unroll
        for (int i = 0; i < 4; ++i) {
            af[i] = *(const bf16x8*)(tA[cur] + rA[i]);
            bf[i] = *(const bf16x8*)(tB[cur] + rB[i]);
        }
        asm volatile("s_waitcnt lgkmcnt(0)" ::: "memory");
        asm volatile("s_barrier" ::: "memory");
        if (kt <= 12) STAGE2((kt + 3) & 3, (kt + 3) * 32);
        #pragma unroll
        for (int i = 0; i < 4; ++i)
            #pragma unroll
            for (int j = 0; j < 4; ++j)
                acc[i][j] = __builtin_amdgcn_mfma_f32_16x16x32_bf16(af[i], bf[j], acc[i][j], 0, 0, 0);
    }
#undef STAGE2

    #pragma unroll
    for (int j = 0; j < 4; ++j) {
        const int col = n0 + wn + j * 16 + l16;
        #pragma unroll
        for (int i = 0; i < 4; ++i) {
            const int rowb = m0 + wm + i * 16 + quad * 4;
            #pragma unroll
            for (int r = 0; r < 4; ++r)
                atomicAdd(&out[(rowb + r) * 512 + col], acc[i][j][r]);
        }
    }
}

// ---------------------------------------------------------------------------
extern "C" void kernel_launch(void* const* d_in, const int* in_sizes, int n_in,
                              void* d_out, int out_size, void* d_ws, size_t ws_size,
                              hipStream_t stream)
{
    (void)in_sizes; (void)n_in; (void)out_size; (void)ws_size;
    const float* x          = (const float*)d_in[0];
    const float* norm_scale = (const float*)d_in[1];
    const float* gate_w     = (const float*)d_in[2];
    const float* gate_b     = (const float*)d_in[3];
    const float* mlp1_w     = (const float*)d_in[4];
    const float* mlp1_b     = (const float*)d_in[5];
    const float* mlp2_w     = (const float*)d_in[6];
    const float* mlp2_b     = (const float*)d_in[7];
    float* out = (float*)d_out;

    char* ws = (char*)d_ws;
    unsigned short* w1p   = (unsigned short*)(ws);              // 8,388,608 B
    unsigned short* w2b   = (unsigned short*)(ws + 8388608);    // 4,194,304 B
    unsigned short* tbf   = (unsigned short*)(ws + 12582912);   // 2,097,152 B
    unsigned short* As    = (unsigned short*)(ws + 14680064);   // 16,777,216 B
    float*          coeff = (float*)(ws + 31457280);            // 65,536 B
    float*          paux  = (float*)(ws + 31522816);            // 49,152 B

    prep_kernel<<<6400, 256, 0, stream>>>(mlp1_w, mlp2_w, w1p, w2b,
                                          x, norm_scale, gate_w, gate_b, mlp2_b,
                                          tbf, coeff, paux, out);
    gemm1_swiglu<<<256, 256, 0, stream>>>(tbf, w1p, mlp1_b, coeff, As);
    gemm2<<<513, 256, 0, stream>>>(As, w2b, out, paux, out + 2048 * 512);
}

// Round 7
// 158.617 us; speedup vs baseline: 1.5848x; 1.1333x over previous
//
#include <hip/hip_runtime.h>
#include <stdint.h>

#define ALPHA 1.702f
#define LIMIT 7.0f

typedef float f32x4 __attribute__((ext_vector_type(4)));
typedef __bf16 bf16x8 __attribute__((ext_vector_type(8)));

static __device__ __forceinline__ unsigned short f2bf(float f) {
    union { float f; uint32_t u; } v; v.f = f;
    uint32_t u = v.u;
    return (unsigned short)((u + 0x7FFFu + ((u >> 16) & 1u)) >> 16);
}

#define GLL16(GP, LP) __builtin_amdgcn_global_load_lds( \
    (const __attribute__((address_space(1))) void*)(GP), \
    (__attribute__((address_space(3))) void*)(LP), 16, 0, 0)

// Conflict-free LDS swizzle (R3-verified: SQ_LDS_BANK_CONFLICT = 0).
static __device__ __forceinline__ int lsw(int row, int kc) {
    return row * 4 + (kc ^ ((row >> 1) & 3));
}

// ---------------------------------------------------------------------------
// prep: blocks [0,6144): fp32->bf16 convert (W1 permuted glu/lin halves).
//       blocks [6144,6400): gate + RMSNorm + coeff + out init + non-atomic
//       aux partials to paux[bid][48]. (No memset launch needed.)
// ---------------------------------------------------------------------------
__global__ __launch_bounds__(256) void prep_kernel(
    const float* __restrict__ w1, const float* __restrict__ w2,
    unsigned short* __restrict__ w1p, unsigned short* __restrict__ w2b,
    const float* __restrict__ x,
    const float* __restrict__ norm_scale,
    const float* __restrict__ gate_w,
    const float* __restrict__ gate_b,
    const float* __restrict__ b2,
    unsigned short* __restrict__ t_bf,
    float* __restrict__ coeff,
    float* __restrict__ paux,     // [256][48]
    float* __restrict__ out)
{
    __shared__ float red[4][48];
    if (blockIdx.x < 6144) {
        const int idx = blockIdx.x * 256 + threadIdx.x;
        const int n1 = 1048576;
        if (idx < n1) {
            const int e = idx >> 17;
            const int rem = idx & 131071;
            const int r = rem >> 7;
            const int c = rem & 127;
            const int src = (r < 512) ? (2 * r) : (2 * (r - 512) + 1);
            float4 v = ((const float4*)w1)[(e << 17) + (src << 7) + c];
            ushort4 o = { f2bf(v.x), f2bf(v.y), f2bf(v.z), f2bf(v.w) };
            ((ushort4*)w1p)[idx] = o;
        } else {
            const int i2 = idx - n1;
            float4 v = ((const float4*)w2)[i2];
            ushort4 o = { f2bf(v.x), f2bf(v.y), f2bf(v.z), f2bf(v.w) };
            ((ushort4*)w2b)[i2] = o;
        }
        return;
    }
    const int bid = blockIdx.x - 6144;
    const int wave = threadIdx.x >> 6;
    const int lane = threadIdx.x & 63;

    float accP[8], accI[8], accC[32];
    #pragma unroll
    for (int e = 0; e < 8; ++e) { accP[e] = 0.f; accI[e] = 0.f; }
    #pragma unroll
    for (int i = 0; i < 32; ++i) accC[i] = 0.f;

    #pragma unroll
    for (int it = 0; it < 2; ++it) {
        const int t = bid * 8 + wave * 2 + it;
        const float4* xr = (const float4*)(x + t * 512);
        float4 x0 = xr[lane * 2];
        float4 x1 = xr[lane * 2 + 1];
        float ss = x0.x*x0.x + x0.y*x0.y + x0.z*x0.z + x0.w*x0.w
                 + x1.x*x1.x + x1.y*x1.y + x1.z*x1.z + x1.w*x1.w;
        #pragma unroll
        for (int off = 32; off > 0; off >>= 1) ss += __shfl_xor(ss, off, 64);
        const float rstd = rsqrtf(ss * (1.f / 512.f) + 1e-6f);
        const float4* sr = (const float4*)norm_scale;
        float4 s0 = sr[lane * 2], s1 = sr[lane * 2 + 1];
        float tv[8];
        tv[0] = x0.x * rstd * s0.x; tv[1] = x0.y * rstd * s0.y;
        tv[2] = x0.z * rstd * s0.z; tv[3] = x0.w * rstd * s0.w;
        tv[4] = x1.x * rstd * s1.x; tv[5] = x1.y * rstd * s1.y;
        tv[6] = x1.z * rstd * s1.z; tv[7] = x1.w * rstd * s1.w;
        uint32_t p0 = (uint32_t)f2bf(tv[0]) | ((uint32_t)f2bf(tv[1]) << 16);
        uint32_t p1 = (uint32_t)f2bf(tv[2]) | ((uint32_t)f2bf(tv[3]) << 16);
        uint32_t p2 = (uint32_t)f2bf(tv[4]) | ((uint32_t)f2bf(tv[5]) << 16);
        uint32_t p3 = (uint32_t)f2bf(tv[6]) | ((uint32_t)f2bf(tv[7]) << 16);
        uint4 pk; pk.x = p0; pk.y = p1; pk.z = p2; pk.w = p3;
        ((uint4*)(t_bf + t * 512))[lane] = pk;
        float le[8];
        #pragma unroll
        for (int e = 0; e < 8; ++e) {
            const float4* gw = (const float4*)(gate_w + e * 512);
            float4 g0 = gw[lane * 2], g1 = gw[lane * 2 + 1];
            float d = tv[0]*g0.x + tv[1]*g0.y + tv[2]*g0.z + tv[3]*g0.w
                    + tv[4]*g1.x + tv[5]*g1.y + tv[6]*g1.z + tv[7]*g1.w;
            #pragma unroll
            for (int off = 32; off > 0; off >>= 1) d += __shfl_xor(d, off, 64);
            le[e] = d + gate_b[e];
        }
        float mx = le[0];
        #pragma unroll
        for (int e = 1; e < 8; ++e) mx = fmaxf(mx, le[e]);
        float pe[8], se = 0.f;
        #pragma unroll
        for (int e = 0; e < 8; ++e) { pe[e] = __expf(le[e] - mx); se += pe[e]; }
        const float sinv = 1.f / se;
        #pragma unroll
        for (int e = 0; e < 8; ++e) pe[e] *= sinv;
        unsigned picked = 0;
        int ik[4]; float wk[4];
        #pragma unroll
        for (int k = 0; k < 4; ++k) {
            float bv = -1.f; int bi = 0;
            #pragma unroll
            for (int e = 0; e < 8; ++e)
                if (!(picked & (1u << e)) && pe[e] > bv) { bv = pe[e]; bi = e; }
            ik[k] = bi; wk[k] = bv; picked |= (1u << bi);
        }
        const float winv = 1.f / (wk[0] + wk[1] + wk[2] + wk[3]);
        float nw[4];
        #pragma unroll
        for (int k = 0; k < 4; ++k) nw[k] = wk[k] * winv;
        float ce[8];
        #pragma unroll
        for (int e = 0; e < 8; ++e) {
            float c = 0.f;
            #pragma unroll
            for (int k = 0; k < 4; ++k) c += (ik[k] == e) ? nw[k] : 0.f;
            ce[e] = c;
        }
        if (lane == 0) {
            #pragma unroll
            for (int e = 0; e < 8; ++e) coeff[t * 8 + e] = ce[e];
        }
        #pragma unroll
        for (int e = 0; e < 8; ++e) { accP[e] += pe[e]; accI[e] += le[e]; }
        #pragma unroll
        for (int k = 0; k < 4; ++k)
            #pragma unroll
            for (int e = 0; e < 8; ++e)
                accC[k * 8 + e] += (ik[k] == e) ? 1.f : 0.f;
        float ov[8];
        ov[0] = x0.x; ov[1] = x0.y; ov[2] = x0.z; ov[3] = x0.w;
        ov[4] = x1.x; ov[5] = x1.y; ov[6] = x1.z; ov[7] = x1.w;
        #pragma unroll
        for (int e = 0; e < 8; ++e) {
            const float4* br = (const float4*)(b2 + e * 512);
            float4 b0 = br[lane * 2], bb1 = br[lane * 2 + 1];
            ov[0] += ce[e] * b0.x; ov[1] += ce[e] * b0.y;
            ov[2] += ce[e] * b0.z; ov[3] += ce[e] * b0.w;
            ov[4] += ce[e] * bb1.x; ov[5] += ce[e] * bb1.y;
            ov[6] += ce[e] * bb1.z; ov[7] += ce[e] * bb1.w;
        }
        float4 o0, o1;
        o0.x = ov[0]; o0.y = ov[1]; o0.z = ov[2]; o0.w = ov[3];
        o1.x = ov[4]; o1.y = ov[5]; o1.z = ov[6]; o1.w = ov[7];
        float4* orow = (float4*)(out + t * 512);
        orow[lane * 2] = o0; orow[lane * 2 + 1] = o1;
    }
    if (lane == 0) {
        #pragma unroll
        for (int e = 0; e < 8; ++e) { red[wave][e] = accP[e]; red[wave][8 + e] = accI[e]; }
        #pragma unroll
        for (int i = 0; i < 32; ++i) red[wave][16 + i] = accC[i];
    }
    __syncthreads();
    if (threadIdx.x < 48) {
        paux[bid * 48 + threadIdx.x] =
            red[0][threadIdx.x] + red[1][threadIdx.x]
          + red[2][threadIdx.x] + red[3][threadIdx.x];
    }
}

// ---------------------------------------------------------------------------
// GEMM1 + swiglu*coeff, R4 pipelined 128x128 structure with XCD-aware tile
// decode: XCD x (= bx&7) owns (e,np) groups 4x..4x+3 -> per-XCD L2 working
// set = 4 W1 slices (1 MB) + all A (2 MB) < 4 MiB. Block 512 = aux loss.
// ---------------------------------------------------------------------------
__global__ __launch_bounds__(256, 2) void gemm1_swiglu(
    const unsigned short* __restrict__ A,    // t_bf [2048][512]
    const unsigned short* __restrict__ w1p,  // [8][1024][512] glu/lin split
    const float* __restrict__ b1,            // [8][1024] interleaved
    const float* __restrict__ coeff,         // [2048][8]
    unsigned short* __restrict__ As,         // [2048][4096]
    const float* __restrict__ paux,          // [256][48]
    float* __restrict__ aux_out)
{
    if (blockIdx.x == 512) {
        __shared__ float sred[4][48];
        const int wv = threadIdx.x >> 6, ln = threadIdx.x & 63;
        if (ln < 48) {
            float s = 0.f;
            for (int b = 0; b < 64; ++b) s += paux[(wv * 64 + b) * 48 + ln];
            sred[wv][ln] = s;
        }
        __syncthreads();
        if (threadIdx.x == 0) {
            float imp[8], sl = 0.f;
            #pragma unroll
            for (int e = 0; e < 8; ++e) {
                float a0 = sred[0][e] + sred[1][e] + sred[2][e] + sred[3][e];
                float P = a0 * (1.f / 2048.f);
                imp[e] = sred[0][8+e] + sred[1][8+e] + sred[2][8+e] + sred[3][8+e];
                float c0 = sred[0][16+e] + sred[1][16+e] + sred[2][16+e] + sred[3][16+e];
                float c1 = sred[0][24+e] + sred[1][24+e] + sred[2][24+e] + sred[3][24+e];
                float c2 = sred[0][32+e] + sred[1][32+e] + sred[2][32+e] + sred[3][32+e];
                float c3 = sred[0][40+e] + sred[1][40+e] + sred[2][40+e] + sred[3][40+e];
                float D = (16.f * c0 + 8.f * c1 + 4.f * c2 + 2.f * c3) * (1.f / 8192.f);
                sl += P * D;
            }
            float loss_load = 0.01f * 8.f * sl;
            float mean = 0.f;
            #pragma unroll
            for (int e = 0; e < 8; ++e) mean += imp[e];
            mean *= 0.125f;
            float var = 0.f;
            #pragma unroll
            for (int e = 0; e < 8; ++e) { float d = imp[e] - mean; var += d * d; }
            var *= (1.f / 7.f);
            float cv = sqrtf(var) / (mean + 1e-6f);
            *aux_out = loss_load + 0.01f * cv * cv;
        }
        return;
    }
    __shared__ unsigned short tA[2][4096];
    __shared__ unsigned short tBg[2][4096];
    __shared__ unsigned short tBl[2][4096];
    const int tid = threadIdx.x;
    const int bx = blockIdx.x;
    // XCD-aware decode: xcd = bx&7 (HW round-robin), slot = bx>>3 (0..63).
    const int xcd = bx & 7;
    const int slot = bx >> 3;
    const int tile_m = slot >> 2;            // 0..15
    const int g = xcd * 4 + (slot & 3);      // (e,np) group 0..31
    const int e = g >> 2;
    const int np = (g & 3) * 128;
    const int m0 = tile_m * 128;
    const int lane = tid & 63, wave = tid >> 6;
    const int wm = (wave & 1) * 64, wn = (wave >> 1) * 64;
    const int quad = lane >> 4, l16 = lane & 15;
    const int srow = tid >> 2;
    const int soff = ((tid & 3) ^ ((tid >> 3) & 3)) * 8;

    const unsigned short* Ar0 = A + (m0 + srow) * 512 + soff;
    const unsigned short* Ar1 = A + (m0 + 64 + srow) * 512 + soff;
    const unsigned short* Bg = w1p + (e * 1024 + np) * 512;
    const unsigned short* Bg0 = Bg + srow * 512 + soff;
    const unsigned short* Bg1 = Bg + (64 + srow) * 512 + soff;
    const unsigned short* Bl0 = Bg0 + 512 * 512;
    const unsigned short* Bl1 = Bg1 + 512 * 512;

    int rA[4], rB[4];
    #pragma unroll
    for (int i = 0; i < 4; ++i) {
        rA[i] = lsw(wm + i * 16 + l16, quad) * 8;
        rB[i] = lsw(wn + i * 16 + l16, quad) * 8;
    }

    f32x4 accG[4][4], accL[4][4];
    #pragma unroll
    for (int i = 0; i < 4; ++i)
        #pragma unroll
        for (int j = 0; j < 4; ++j) {
            f32x4 z = {0.f, 0.f, 0.f, 0.f};
            accG[i][j] = z; accL[i][j] = z;
        }

#define STAGE1(s, k0) do { \
    GLL16(Ar0 + (k0), tA[s] + tid * 8); \
    GLL16(Ar1 + (k0), tA[s] + (tid + 256) * 8); \
    GLL16(Bg0 + (k0), tBg[s] + tid * 8); \
    GLL16(Bg1 + (k0), tBg[s] + (tid + 256) * 8); \
    GLL16(Bl0 + (k0), tBl[s] + tid * 8); \
    GLL16(Bl1 + (k0), tBl[s] + (tid + 256) * 8); \
} while (0)

    STAGE1(0, 0);
    STAGE1(1, 32);
    #pragma unroll
    for (int kt = 0; kt < 16; ++kt) {
        const int cur = kt & 1;
        if (kt < 15) asm volatile("s_waitcnt vmcnt(6)" ::: "memory");
        else         asm volatile("s_waitcnt vmcnt(0)" ::: "memory");
        asm volatile("s_barrier" ::: "memory");
        bf16x8 af[4], bg[4], bl[4];
        #pragma unroll
        for (int i = 0; i < 4; ++i) {
            af[i] = *(const bf16x8*)(tA[cur] + rA[i]);
            bg[i] = *(const bf16x8*)(tBg[cur] + rB[i]);
            bl[i] = *(const bf16x8*)(tBl[cur] + rB[i]);
        }
        asm volatile("s_waitcnt lgkmcnt(0)" ::: "memory");
        asm volatile("s_barrier" ::: "memory");
        if (kt < 14) STAGE1(cur, (kt + 2) * 32);
        #pragma unroll
        for (int i = 0; i < 4; ++i)
            #pragma unroll
            for (int j = 0; j < 4; ++j) {
                accG[i][j] = __builtin_amdgcn_mfma_f32_16x16x32_bf16(af[i], bg[j], accG[i][j], 0, 0, 0);
                accL[i][j] = __builtin_amdgcn_mfma_f32_16x16x32_bf16(af[i], bl[j], accL[i][j], 0, 0, 0);
            }
    }
#undef STAGE1

    float cw[4][4];
    #pragma unroll
    for (int i = 0; i < 4; ++i) {
        const int rowb = m0 + wm + i * 16 + quad * 4;
        #pragma unroll
        for (int r = 0; r < 4; ++r) cw[i][r] = coeff[(rowb + r) * 8 + e];
    }
    #pragma unroll
    for (int j = 0; j < 4; ++j) {
        const int colp = np + wn + j * 16 + l16;
        const float bgv = b1[e * 1024 + 2 * colp];
        const float blv = b1[e * 1024 + 2 * colp + 1];
        #pragma unroll
        for (int i = 0; i < 4; ++i) {
            const int rowb = m0 + wm + i * 16 + quad * 4;
            #pragma unroll
            for (int r = 0; r < 4; ++r) {
                float g2 = fminf(fmaxf(accG[i][j][r] + bgv, -LIMIT), LIMIT);
                float l2 = fminf(fmaxf(accL[i][j][r] + blv, -LIMIT), LIMIT);
                float a = g2 / (1.f + __expf(-ALPHA * g2)) + l2 + 1.f;
                a *= cw[i][r];
                As[(rowb + r) * 4096 + e * 512 + colp] = f2bf(a);
            }
        }
    }
}

// ---------------------------------------------------------------------------
// GEMM2 split-K=8, R4 pipelined structure with XCD-aware decode: XCD x owns
// expert e=x -> per-XCD working set = W2[e] (512 KB) + As e-slice (2 MB).
// fp32 atomicAdd into pre-initialized out. grid 512.
// ---------------------------------------------------------------------------
__global__ __launch_bounds__(256, 2) void gemm2(
    const unsigned short* __restrict__ As,  // [2048][4096]
    const unsigned short* __restrict__ w2b, // [8][512][512]
    float* __restrict__ out)                // [2048][512]
{
    __shared__ unsigned short tA[2][4096];
    __shared__ unsigned short tB[2][4096];
    const int tid = threadIdx.x;
    const int bx = blockIdx.x;
    // XCD-aware: e = bx&7, slot decodes (m,n)
    const int e = bx & 7;
    const int slot = bx >> 3;
    const int tile_m = slot >> 2;           // 0..15
    const int tile_n = slot & 3;            // 0..3
    const int m0 = tile_m * 128, n0 = tile_n * 128;
    const int lane = tid & 63, wave = tid >> 6;
    const int wm = (wave & 1) * 64, wn = (wave >> 1) * 64;
    const int quad = lane >> 4, l16 = lane & 15;
    const int srow = tid >> 2;
    const int soff = ((tid & 3) ^ ((tid >> 3) & 3)) * 8;

    const unsigned short* Ar0 = As + (m0 + srow) * 4096 + e * 512 + soff;
    const unsigned short* Ar1 = As + (m0 + 64 + srow) * 4096 + e * 512 + soff;
    const unsigned short* Bb  = w2b + e * 262144;
    const unsigned short* Br0 = Bb + (n0 + srow) * 512 + soff;
    const unsigned short* Br1 = Bb + (n0 + 64 + srow) * 512 + soff;

    int rA[4], rB[4];
    #pragma unroll
    for (int i = 0; i < 4; ++i) {
        rA[i] = lsw(wm + i * 16 + l16, quad) * 8;
        rB[i] = lsw(wn + i * 16 + l16, quad) * 8;
    }

    f32x4 acc[4][4];
    #pragma unroll
    for (int i = 0; i < 4; ++i)
        #pragma unroll
        for (int j = 0; j < 4; ++j) { f32x4 z = {0.f, 0.f, 0.f, 0.f}; acc[i][j] = z; }

#define STAGE2(s, k0) do { \
    GLL16(Ar0 + (k0), tA[s] + tid * 8); \
    GLL16(Ar1 + (k0), tA[s] + (tid + 256) * 8); \
    GLL16(Br0 + (k0), tB[s] + tid * 8); \
    GLL16(Br1 + (k0), tB[s] + (tid + 256) * 8); \
} while (0)

    STAGE2(0, 0);
    STAGE2(1, 32);
    #pragma unroll
    for (int kt = 0; kt < 16; ++kt) {
        const int cur = kt & 1;
        if (kt < 15) asm volatile("s_waitcnt vmcnt(4)" ::: "memory");
        else         asm volatile("s_waitcnt vmcnt(0)" ::: "memory");
        asm volatile("s_barrier" ::: "memory");
        bf16x8 af[4], bf[4];
        #pragma unroll
        for (int i = 0; i < 4; ++i) {
            af[i] = *(const bf16x8*)(tA[cur] + rA[i]);
            bf[i] = *(const bf16x8*)(tB[cur] + rB[i]);
        }
        asm volatile("s_waitcnt lgkmcnt(0)" ::: "memory");
        asm volatile("s_barrier" ::: "memory");
        if (kt < 14) STAGE2(cur, (kt + 2) * 32);
        #pragma unroll
        for (int i = 0; i < 4; ++i)
            #pragma unroll
            for (int j = 0; j < 4; ++j)
                acc[i][j] = __builtin_amdgcn_mfma_f32_16x16x32_bf16(af[i], bf[j], acc[i][j], 0, 0, 0);
    }
#undef STAGE2

    #pragma unroll
    for (int j = 0; j < 4; ++j) {
        const int col = n0 + wn + j * 16 + l16;
        #pragma unroll
        for (int i = 0; i < 4; ++i) {
            const int rowb = m0 + wm + i * 16 + quad * 4;
            #pragma unroll
            for (int r = 0; r < 4; ++r)
                atomicAdd(&out[(rowb + r) * 512 + col], acc[i][j][r]);
        }
    }
}

// ---------------------------------------------------------------------------
extern "C" void kernel_launch(void* const* d_in, const int* in_sizes, int n_in,
                              void* d_out, int out_size, void* d_ws, size_t ws_size,
                              hipStream_t stream)
{
    (void)in_sizes; (void)n_in; (void)out_size; (void)ws_size;
    const float* x          = (const float*)d_in[0];
    const float* norm_scale = (const float*)d_in[1];
    const float* gate_w     = (const float*)d_in[2];
    const float* gate_b     = (const float*)d_in[3];
    const float* mlp1_w     = (const float*)d_in[4];
    const float* mlp1_b     = (const float*)d_in[5];
    const float* mlp2_w     = (const float*)d_in[6];
    const float* mlp2_b     = (const float*)d_in[7];
    float* out = (float*)d_out;

    char* ws = (char*)d_ws;
    unsigned short* w1p   = (unsigned short*)(ws);              // 8,388,608 B
    unsigned short* w2b   = (unsigned short*)(ws + 8388608);    // 4,194,304 B
    unsigned short* tbf   = (unsigned short*)(ws + 12582912);   // 2,097,152 B
    unsigned short* As    = (unsigned short*)(ws + 14680064);   // 16,777,216 B
    float*          coeff = (float*)(ws + 31457280);            // 65,536 B
    float*          paux  = (float*)(ws + 31522816);            // 49,152 B

    prep_kernel<<<6400, 256, 0, stream>>>(mlp1_w, mlp2_w, w1p, w2b,
                                          x, norm_scale, gate_w, gate_b, mlp2_b,
                                          tbf, coeff, paux, out);
    gemm1_swiglu<<<513, 256, 0, stream>>>(tbf, w1p, mlp1_b, coeff, As,
                                          paux, out + 2048 * 512);
    gemm2<<<512, 256, 0, stream>>>(As, w2b, out);
}

// Round 8
// 153.127 us; speedup vs baseline: 1.6416x; 1.0359x over previous
//
#include <hip/hip_runtime.h>
#include <stdint.h>

#define ALPHA 1.702f
#define LIMIT 7.0f

typedef float f32x4 __attribute__((ext_vector_type(4)));
typedef __bf16 bf16x8 __attribute__((ext_vector_type(8)));

static __device__ __forceinline__ unsigned short f2bf(float f) {
    union { float f; uint32_t u; } v; v.f = f;
    uint32_t u = v.u;
    return (unsigned short)((u + 0x7FFFu + ((u >> 16) & 1u)) >> 16);
}
static __device__ __forceinline__ int imin(int a, int b) { return a < b ? a : b; }

#define GLL16(GP, LP) __builtin_amdgcn_global_load_lds( \
    (const __attribute__((address_space(1))) void*)(GP), \
    (__attribute__((address_space(3))) void*)(LP), 16, 0, 0)

// Conflict-free LDS swizzle (R3-verified: SQ_LDS_BANK_CONFLICT = 0).
static __device__ __forceinline__ int lsw(int row, int kc) {
    return row * 4 + (kc ^ ((row >> 1) & 3));
}

// ---------------------------------------------------------------------------
// prep: blocks [0,6144): fp32->bf16 convert (W1 permuted glu/lin halves).
//       blocks [6144,6400): gate -> compact per-expert token lists (idx,
//       wcoef, cnt), non-atomic aux partials paux[bid][48], out init.
// ---------------------------------------------------------------------------
__global__ __launch_bounds__(256) void prep_kernel(
    const float* __restrict__ w1, const float* __restrict__ w2,
    unsigned short* __restrict__ w1p, unsigned short* __restrict__ w2b,
    const float* __restrict__ x,
    const float* __restrict__ norm_scale,
    const float* __restrict__ gate_w,
    const float* __restrict__ gate_b,
    const float* __restrict__ b2,
    unsigned short* __restrict__ t_bf,
    int* __restrict__ idx,        // [8][2048]
    float* __restrict__ wcoef,    // [8][2048]
    int* __restrict__ cnt,        // [8] (pre-zeroed by memset)
    float* __restrict__ paux,     // [256][48]
    float* __restrict__ out)
{
    __shared__ float red[4][48];
    __shared__ int   ltok[8][8];
    __shared__ float lwt[8][8];
    __shared__ int   lcnt[8];
    __shared__ int   gbase[8];
    if (blockIdx.x < 6144) {
        const int i4 = blockIdx.x * 256 + threadIdx.x;
        const int n1 = 1048576;
        if (i4 < n1) {
            const int e = i4 >> 17;
            const int rem = i4 & 131071;
            const int r = rem >> 7;
            const int c = rem & 127;
            const int src = (r < 512) ? (2 * r) : (2 * (r - 512) + 1);
            float4 v = ((const float4*)w1)[(e << 17) + (src << 7) + c];
            ushort4 o = { f2bf(v.x), f2bf(v.y), f2bf(v.z), f2bf(v.w) };
            ((ushort4*)w1p)[i4] = o;
        } else {
            const int i2 = i4 - n1;
            float4 v = ((const float4*)w2)[i2];
            ushort4 o = { f2bf(v.x), f2bf(v.y), f2bf(v.z), f2bf(v.w) };
            ((ushort4*)w2b)[i2] = o;
        }
        return;
    }
    const int bid = blockIdx.x - 6144;
    const int wave = threadIdx.x >> 6;
    const int lane = threadIdx.x & 63;
    if (threadIdx.x < 8) lcnt[threadIdx.x] = 0;
    __syncthreads();

    float accP[8], accI[8], accC[32];
    #pragma unroll
    for (int e = 0; e < 8; ++e) { accP[e] = 0.f; accI[e] = 0.f; }
    #pragma unroll
    for (int i = 0; i < 32; ++i) accC[i] = 0.f;

    #pragma unroll
    for (int it = 0; it < 2; ++it) {
        const int t = bid * 8 + wave * 2 + it;
        const float4* xr = (const float4*)(x + t * 512);
        float4 x0 = xr[lane * 2];
        float4 x1 = xr[lane * 2 + 1];
        float ss = x0.x*x0.x + x0.y*x0.y + x0.z*x0.z + x0.w*x0.w
                 + x1.x*x1.x + x1.y*x1.y + x1.z*x1.z + x1.w*x1.w;
        #pragma unroll
        for (int off = 32; off > 0; off >>= 1) ss += __shfl_xor(ss, off, 64);
        const float rstd = rsqrtf(ss * (1.f / 512.f) + 1e-6f);
        const float4* sr = (const float4*)norm_scale;
        float4 s0 = sr[lane * 2], s1 = sr[lane * 2 + 1];
        float tv[8];
        tv[0] = x0.x * rstd * s0.x; tv[1] = x0.y * rstd * s0.y;
        tv[2] = x0.z * rstd * s0.z; tv[3] = x0.w * rstd * s0.w;
        tv[4] = x1.x * rstd * s1.x; tv[5] = x1.y * rstd * s1.y;
        tv[6] = x1.z * rstd * s1.z; tv[7] = x1.w * rstd * s1.w;
        uint32_t p0 = (uint32_t)f2bf(tv[0]) | ((uint32_t)f2bf(tv[1]) << 16);
        uint32_t p1 = (uint32_t)f2bf(tv[2]) | ((uint32_t)f2bf(tv[3]) << 16);
        uint32_t p2 = (uint32_t)f2bf(tv[4]) | ((uint32_t)f2bf(tv[5]) << 16);
        uint32_t p3 = (uint32_t)f2bf(tv[6]) | ((uint32_t)f2bf(tv[7]) << 16);
        uint4 pk; pk.x = p0; pk.y = p1; pk.z = p2; pk.w = p3;
        ((uint4*)(t_bf + t * 512))[lane] = pk;
        float le[8];
        #pragma unroll
        for (int e = 0; e < 8; ++e) {
            const float4* gw = (const float4*)(gate_w + e * 512);
            float4 g0 = gw[lane * 2], g1 = gw[lane * 2 + 1];
            float d = tv[0]*g0.x + tv[1]*g0.y + tv[2]*g0.z + tv[3]*g0.w
                    + tv[4]*g1.x + tv[5]*g1.y + tv[6]*g1.z + tv[7]*g1.w;
            #pragma unroll
            for (int off = 32; off > 0; off >>= 1) d += __shfl_xor(d, off, 64);
            le[e] = d + gate_b[e];
        }
        float mx = le[0];
        #pragma unroll
        for (int e = 1; e < 8; ++e) mx = fmaxf(mx, le[e]);
        float pe[8], se = 0.f;
        #pragma unroll
        for (int e = 0; e < 8; ++e) { pe[e] = __expf(le[e] - mx); se += pe[e]; }
        const float sinv = 1.f / se;
        #pragma unroll
        for (int e = 0; e < 8; ++e) pe[e] *= sinv;
        unsigned picked = 0;
        int ik[4]; float wk[4];
        #pragma unroll
        for (int k = 0; k < 4; ++k) {
            float bv = -1.f; int bi = 0;
            #pragma unroll
            for (int e = 0; e < 8; ++e)
                if (!(picked & (1u << e)) && pe[e] > bv) { bv = pe[e]; bi = e; }
            ik[k] = bi; wk[k] = bv; picked |= (1u << bi);
        }
        const float winv = 1.f / (wk[0] + wk[1] + wk[2] + wk[3]);
        float nw[4];
        #pragma unroll
        for (int k = 0; k < 4; ++k) nw[k] = wk[k] * winv;
        float ce[8];
        #pragma unroll
        for (int e = 0; e < 8; ++e) {
            float c = 0.f;
            #pragma unroll
            for (int k = 0; k < 4; ++k) c += (ik[k] == e) ? nw[k] : 0.f;
            ce[e] = c;
        }
        if (lane == 0) {
            #pragma unroll
            for (int k = 0; k < 4; ++k) {
                const int e = ik[k];
                const int pos = atomicAdd(&lcnt[e], 1);
                ltok[e][pos] = t; lwt[e][pos] = nw[k];
            }
        }
        #pragma unroll
        for (int e = 0; e < 8; ++e) { accP[e] += pe[e]; accI[e] += le[e]; }
        #pragma unroll
        for (int k = 0; k < 4; ++k)
            #pragma unroll
            for (int e = 0; e < 8; ++e)
                accC[k * 8 + e] += (ik[k] == e) ? 1.f : 0.f;
        float ov[8];
        ov[0] = x0.x; ov[1] = x0.y; ov[2] = x0.z; ov[3] = x0.w;
        ov[4] = x1.x; ov[5] = x1.y; ov[6] = x1.z; ov[7] = x1.w;
        #pragma unroll
        for (int e = 0; e < 8; ++e) {
            const float4* br = (const float4*)(b2 + e * 512);
            float4 b0 = br[lane * 2], bb1 = br[lane * 2 + 1];
            ov[0] += ce[e] * b0.x; ov[1] += ce[e] * b0.y;
            ov[2] += ce[e] * b0.z; ov[3] += ce[e] * b0.w;
            ov[4] += ce[e] * bb1.x; ov[5] += ce[e] * bb1.y;
            ov[6] += ce[e] * bb1.z; ov[7] += ce[e] * bb1.w;
        }
        float4 o0, o1;
        o0.x = ov[0]; o0.y = ov[1]; o0.z = ov[2]; o0.w = ov[3];
        o1.x = ov[4]; o1.y = ov[5]; o1.z = ov[6]; o1.w = ov[7];
        float4* orow = (float4*)(out + t * 512);
        orow[lane * 2] = o0; orow[lane * 2 + 1] = o1;
    }
    if (lane == 0) {
        #pragma unroll
        for (int e = 0; e < 8; ++e) { red[wave][e] = accP[e]; red[wave][8 + e] = accI[e]; }
        #pragma unroll
        for (int i = 0; i < 32; ++i) red[wave][16 + i] = accC[i];
    }
    __syncthreads();
    if (threadIdx.x < 8)
        gbase[threadIdx.x] = atomicAdd(&cnt[threadIdx.x], lcnt[threadIdx.x]);
    __syncthreads();
    if (threadIdx.x < 64) {
        const int e = threadIdx.x >> 3, i = threadIdx.x & 7;
        if (i < lcnt[e]) {
            const int g = gbase[e] + i;
            idx[e * 2048 + g] = ltok[e][i];
            wcoef[e * 2048 + g] = lwt[e][i];
        }
    }
    if (threadIdx.x < 48) {
        paux[bid * 48 + threadIdx.x] =
            red[0][threadIdx.x] + red[1][threadIdx.x]
          + red[2][threadIdx.x] + red[3][threadIdx.x];
    }
}

// ---------------------------------------------------------------------------
// GEMM1 (routed) + swiglu*wcoef. grid 513 = 8e x 16m x 4n (+ block 512 aux).
// XCD = bx&7 = expert -> per-XCD L2 WS = W1[e] 2 MB + gathered t_bf ~1 MB.
// Blocks with m0 >= cnt[e] exit (~half). 128x128 tiles, R4 pipelined K-loop.
// ---------------------------------------------------------------------------
__global__ __launch_bounds__(256, 2) void gemm1_swiglu(
    const unsigned short* __restrict__ A,    // t_bf [2048][512]
    const unsigned short* __restrict__ w1p,  // [8][1024][512] glu/lin split
    const float* __restrict__ b1,            // [8][1024] interleaved
    const int* __restrict__ idx,             // [8][2048]
    const float* __restrict__ wcoef,         // [8][2048]
    const int* __restrict__ cnt,             // [8]
    unsigned short* __restrict__ As,         // [8][2048][512] compact
    const float* __restrict__ paux,          // [256][48]
    float* __restrict__ aux_out)
{
    if (blockIdx.x == 512) {
        __shared__ float sred[4][48];
        const int wv = threadIdx.x >> 6, ln = threadIdx.x & 63;
        if (ln < 48) {
            float s = 0.f;
            for (int b = 0; b < 64; ++b) s += paux[(wv * 64 + b) * 48 + ln];
            sred[wv][ln] = s;
        }
        __syncthreads();
        if (threadIdx.x == 0) {
            float imp[8], sl = 0.f;
            #pragma unroll
            for (int e = 0; e < 8; ++e) {
                float a0 = sred[0][e] + sred[1][e] + sred[2][e] + sred[3][e];
                float P = a0 * (1.f / 2048.f);
                imp[e] = sred[0][8+e] + sred[1][8+e] + sred[2][8+e] + sred[3][8+e];
                float c0 = sred[0][16+e] + sred[1][16+e] + sred[2][16+e] + sred[3][16+e];
                float c1 = sred[0][24+e] + sred[1][24+e] + sred[2][24+e] + sred[3][24+e];
                float c2 = sred[0][32+e] + sred[1][32+e] + sred[2][32+e] + sred[3][32+e];
                float c3 = sred[0][40+e] + sred[1][40+e] + sred[2][40+e] + sred[3][40+e];
                float D = (16.f * c0 + 8.f * c1 + 4.f * c2 + 2.f * c3) * (1.f / 8192.f);
                sl += P * D;
            }
            float loss_load = 0.01f * 8.f * sl;
            float mean = 0.f;
            #pragma unroll
            for (int e = 0; e < 8; ++e) mean += imp[e];
            mean *= 0.125f;
            float var = 0.f;
            #pragma unroll
            for (int e = 0; e < 8; ++e) { float d = imp[e] - mean; var += d * d; }
            var *= (1.f / 7.f);
            float cv = sqrtf(var) / (mean + 1e-6f);
            *aux_out = loss_load + 0.01f * cv * cv;
        }
        return;
    }
    const int bx = blockIdx.x;
    const int e = bx & 7;
    const int slot = bx >> 3;
    const int tile_m = slot >> 2, tile_n = slot & 3;
    const int m0 = tile_m * 128, np = tile_n * 128;
    const int cnte = cnt[e];
    if (m0 >= cnte) return;

    __shared__ unsigned short tA[2][4096];
    __shared__ unsigned short tBg[2][4096];
    __shared__ unsigned short tBl[2][4096];
    const int tid = threadIdx.x;
    const int lane = tid & 63, wave = tid >> 6;
    const int wm = (wave & 1) * 64, wn = (wave >> 1) * 64;
    const int quad = lane >> 4, l16 = lane & 15;
    const int srow = tid >> 2;
    const int soff = ((tid & 3) ^ ((tid >> 3) & 3)) * 8;

    const int tok0 = idx[e * 2048 + imin(m0 + srow, cnte - 1)];
    const int tok1 = idx[e * 2048 + imin(m0 + 64 + srow, cnte - 1)];
    const unsigned short* Ar0 = A + tok0 * 512 + soff;
    const unsigned short* Ar1 = A + tok1 * 512 + soff;
    const unsigned short* Bg = w1p + (e * 1024 + np) * 512;
    const unsigned short* Bg0 = Bg + srow * 512 + soff;
    const unsigned short* Bg1 = Bg + (64 + srow) * 512 + soff;
    const unsigned short* Bl0 = Bg0 + 512 * 512;
    const unsigned short* Bl1 = Bg1 + 512 * 512;

    int rA[4], rB[4];
    #pragma unroll
    for (int i = 0; i < 4; ++i) {
        rA[i] = lsw(wm + i * 16 + l16, quad) * 8;
        rB[i] = lsw(wn + i * 16 + l16, quad) * 8;
    }

    f32x4 accG[4][4], accL[4][4];
    #pragma unroll
    for (int i = 0; i < 4; ++i)
        #pragma unroll
        for (int j = 0; j < 4; ++j) {
            f32x4 z = {0.f, 0.f, 0.f, 0.f};
            accG[i][j] = z; accL[i][j] = z;
        }

#define STAGE1(s, k0) do { \
    GLL16(Ar0 + (k0), tA[s] + tid * 8); \
    GLL16(Ar1 + (k0), tA[s] + (tid + 256) * 8); \
    GLL16(Bg0 + (k0), tBg[s] + tid * 8); \
    GLL16(Bg1 + (k0), tBg[s] + (tid + 256) * 8); \
    GLL16(Bl0 + (k0), tBl[s] + tid * 8); \
    GLL16(Bl1 + (k0), tBl[s] + (tid + 256) * 8); \
} while (0)

    STAGE1(0, 0);
    STAGE1(1, 32);
    #pragma unroll
    for (int kt = 0; kt < 16; ++kt) {
        const int cur = kt & 1;
        if (kt < 15) asm volatile("s_waitcnt vmcnt(6)" ::: "memory");
        else         asm volatile("s_waitcnt vmcnt(0)" ::: "memory");
        asm volatile("s_barrier" ::: "memory");
        bf16x8 af[4], bg[4], bl[4];
        #pragma unroll
        for (int i = 0; i < 4; ++i) {
            af[i] = *(const bf16x8*)(tA[cur] + rA[i]);
            bg[i] = *(const bf16x8*)(tBg[cur] + rB[i]);
            bl[i] = *(const bf16x8*)(tBl[cur] + rB[i]);
        }
        asm volatile("s_waitcnt lgkmcnt(0)" ::: "memory");
        asm volatile("s_barrier" ::: "memory");
        if (kt < 14) STAGE1(cur, (kt + 2) * 32);
        #pragma unroll
        for (int i = 0; i < 4; ++i)
            #pragma unroll
            for (int j = 0; j < 4; ++j) {
                accG[i][j] = __builtin_amdgcn_mfma_f32_16x16x32_bf16(af[i], bg[j], accG[i][j], 0, 0, 0);
                accL[i][j] = __builtin_amdgcn_mfma_f32_16x16x32_bf16(af[i], bl[j], accL[i][j], 0, 0, 0);
            }
    }
#undef STAGE1

    #pragma unroll
    for (int j = 0; j < 4; ++j) {
        const int colp = np + wn + j * 16 + l16;
        const float bgv = b1[e * 1024 + 2 * colp];
        const float blv = b1[e * 1024 + 2 * colp + 1];
        #pragma unroll
        for (int i = 0; i < 4; ++i) {
            const int sb = m0 + wm + i * 16 + quad * 4;
            #pragma unroll
            for (int r = 0; r < 4; ++r) {
                const int s = sb + r;
                if (s < cnte) {
                    float g2 = fminf(fmaxf(accG[i][j][r] + bgv, -LIMIT), LIMIT);
                    float l2 = fminf(fmaxf(accL[i][j][r] + blv, -LIMIT), LIMIT);
                    float a = g2 / (1.f + __expf(-ALPHA * g2)) + l2 + 1.f;
                    a *= wcoef[e * 2048 + s];
                    As[e * 1048576 + s * 512 + colp] = f2bf(a);
                }
            }
        }
    }
}

// ---------------------------------------------------------------------------
// GEMM2 (routed): grid 512 = 8e x 16m x 4n, XCD = e. Compact As rows,
// K=512 (expert I-dim), scatter fp32 atomicAdd into pre-initialized out.
// Poisoned As rows (s >= cnt[e]) are finite tiny bf16 garbage; rows are
// independent in MFMA and masked at scatter.
// ---------------------------------------------------------------------------
__global__ __launch_bounds__(256, 2) void gemm2(
    const unsigned short* __restrict__ As,  // [8][2048][512] compact
    const unsigned short* __restrict__ w2b, // [8][512][512]
    const int* __restrict__ idx,            // [8][2048]
    const int* __restrict__ cnt,            // [8]
    float* __restrict__ out)                // [2048][512]
{
    const int bx = blockIdx.x;
    const int e = bx & 7;
    const int slot = bx >> 3;
    const int tile_m = slot >> 2, tile_n = slot & 3;
    const int m0 = tile_m * 128, n0 = tile_n * 128;
    const int cnte = cnt[e];
    if (m0 >= cnte) return;

    __shared__ unsigned short tA[2][4096];
    __shared__ unsigned short tB[2][4096];
    const int tid = threadIdx.x;
    const int lane = tid & 63, wave = tid >> 6;
    const int wm = (wave & 1) * 64, wn = (wave >> 1) * 64;
    const int quad = lane >> 4, l16 = lane & 15;
    const int srow = tid >> 2;
    const int soff = ((tid & 3) ^ ((tid >> 3) & 3)) * 8;

    const unsigned short* Ar0 = As + e * 1048576 + (m0 + srow) * 512 + soff;
    const unsigned short* Ar1 = As + e * 1048576 + (m0 + 64 + srow) * 512 + soff;
    const unsigned short* Bb  = w2b + e * 262144;
    const unsigned short* Br0 = Bb + (n0 + srow) * 512 + soff;
    const unsigned short* Br1 = Bb + (n0 + 64 + srow) * 512 + soff;

    int rA[4], rB[4];
    #pragma unroll
    for (int i = 0; i < 4; ++i) {
        rA[i] = lsw(wm + i * 16 + l16, quad) * 8;
        rB[i] = lsw(wn + i * 16 + l16, quad) * 8;
    }

    f32x4 acc[4][4];
    #pragma unroll
    for (int i = 0; i < 4; ++i)
        #pragma unroll
        for (int j = 0; j < 4; ++j) { f32x4 z = {0.f, 0.f, 0.f, 0.f}; acc[i][j] = z; }

#define STAGE2(s, k0) do { \
    GLL16(Ar0 + (k0), tA[s] + tid * 8); \
    GLL16(Ar1 + (k0), tA[s] + (tid + 256) * 8); \
    GLL16(Br0 + (k0), tB[s] + tid * 8); \
    GLL16(Br1 + (k0), tB[s] + (tid + 256) * 8); \
} while (0)

    STAGE2(0, 0);
    STAGE2(1, 32);
    #pragma unroll
    for (int kt = 0; kt < 16; ++kt) {
        const int cur = kt & 1;
        if (kt < 15) asm volatile("s_waitcnt vmcnt(4)" ::: "memory");
        else         asm volatile("s_waitcnt vmcnt(0)" ::: "memory");
        asm volatile("s_barrier" ::: "memory");
        bf16x8 af[4], bf[4];
        #pragma unroll
        for (int i = 0; i < 4; ++i) {
            af[i] = *(const bf16x8*)(tA[cur] + rA[i]);
            bf[i] = *(const bf16x8*)(tB[cur] + rB[i]);
        }
        asm volatile("s_waitcnt lgkmcnt(0)" ::: "memory");
        asm volatile("s_barrier" ::: "memory");
        if (kt < 14) STAGE2(cur, (kt + 2) * 32);
        #pragma unroll
        for (int i = 0; i < 4; ++i)
            #pragma unroll
            for (int j = 0; j < 4; ++j)
                acc[i][j] = __builtin_amdgcn_mfma_f32_16x16x32_bf16(af[i], bf[j], acc[i][j], 0, 0, 0);
    }
#undef STAGE2

    #pragma unroll
    for (int i = 0; i < 4; ++i) {
        const int sb = m0 + wm + i * 16 + quad * 4;
        #pragma unroll
        for (int r = 0; r < 4; ++r) {
            const int s = sb + r;
            if (s < cnte) {
                const int tok = idx[e * 2048 + s];
                #pragma unroll
                for (int j = 0; j < 4; ++j) {
                    const int col = n0 + wn + j * 16 + l16;
                    atomicAdd(&out[tok * 512 + col], acc[i][j][r]);
                }
            }
        }
    }
}

// ---------------------------------------------------------------------------
extern "C" void kernel_launch(void* const* d_in, const int* in_sizes, int n_in,
                              void* d_out, int out_size, void* d_ws, size_t ws_size,
                              hipStream_t stream)
{
    (void)in_sizes; (void)n_in; (void)out_size; (void)ws_size;
    const float* x          = (const float*)d_in[0];
    const float* norm_scale = (const float*)d_in[1];
    const float* gate_w     = (const float*)d_in[2];
    const float* gate_b     = (const float*)d_in[3];
    const float* mlp1_w     = (const float*)d_in[4];
    const float* mlp1_b     = (const float*)d_in[5];
    const float* mlp2_w     = (const float*)d_in[6];
    const float* mlp2_b     = (const float*)d_in[7];
    float* out = (float*)d_out;

    char* ws = (char*)d_ws;
    unsigned short* w1p   = (unsigned short*)(ws);              // 8,388,608 B
    unsigned short* w2b   = (unsigned short*)(ws + 8388608);    // 4,194,304 B
    unsigned short* tbf   = (unsigned short*)(ws + 12582912);   // 2,097,152 B
    unsigned short* As    = (unsigned short*)(ws + 14680064);   // 16,777,216 B
    int*            idx   = (int*)(ws + 31457280);              // 65,536 B
    float*          wcoef = (float*)(ws + 31522816);            // 65,536 B
    float*          paux  = (float*)(ws + 31588352);            // 49,152 B
    int*            cnt   = (int*)(ws + 31637504);              // 32 B

    hipMemsetAsync(cnt, 0, 32, stream);
    prep_kernel<<<6400, 256, 0, stream>>>(mlp1_w, mlp2_w, w1p, w2b,
                                          x, norm_scale, gate_w, gate_b, mlp2_b,
                                          tbf, idx, wcoef, cnt, paux, out);
    gemm1_swiglu<<<513, 256, 0, stream>>>(tbf, w1p, mlp1_b, idx, wcoef, cnt,
                                          As, paux, out + 2048 * 512);
    gemm2<<<512, 256, 0, stream>>>(As, w2b, idx, cnt, out);
}